// Round 6
// baseline (263.234 us; speedup 1.0000x reference)
//
#include <hip/hip_runtime.h>
#include <hip/hip_fp16.h>

typedef float    f4 __attribute__((ext_vector_type(4)));
typedef unsigned u4 __attribute__((ext_vector_type(4)));

__device__ __forceinline__ float2 cadd(float2 a, float2 b) { return make_float2(a.x + b.x, a.y + b.y); }
__device__ __forceinline__ float2 csub(float2 a, float2 b) { return make_float2(a.x - b.x, a.y - b.y); }
__device__ __forceinline__ float2 cmul(float2 w, float2 z) {
    return make_float2(w.x * z.x - w.y * z.y, w.x * z.y + w.y * z.x);
}
__device__ __forceinline__ unsigned pk(float2 z) {
    __half2 h = __floats2half2_rn(z.x, z.y);
    return *reinterpret_cast<unsigned*>(&h);
}
__device__ __forceinline__ float2 upk(unsigned u) {
    __half2 h = *reinterpret_cast<__half2*>(&u);
    return __half22float2(h);
}

__host__ __device__ constexpr unsigned crev(unsigned x, int bits) {
    unsigned r = 0;
    for (int k = 0; k < bits; ++k) r |= ((x >> k) & 1u) << (bits - 1 - k);
    return r;
}

// cross-lane butterfly: pair (lane, lane^m); hi-lane holds the multiplied leg.
__device__ __forceinline__ float2 sbfly(float2 x, int m, bool hi, float s, float2 wv) {
    float2 o;
    o.x = __shfl_xor(x.x, m);
    o.y = __shfl_xor(x.y, m);
    const float2 a = hi ? o : x;     // un-multiplied leg
    const float2 b = hi ? x : o;     // multiplied leg
    const float2 p = cmul(wv, b);
    return make_float2(fmaf(s, p.x, a.x), fmaf(s, p.y, a.y));
}

// Butterfly network (DIF):
//   stage t (0..22): pairs (i, i + 2^(22-t)); z'[i] = z[i] + w*z[i+D]; z'[i+D] = z[i] - w*z[i+D]
//   w = weight[ bitrev_t(i >> (23-t)) * 2^(22-t) ];  final: out[rev23(i)] = z[i]
// Split: A: t=0..7 (bits 22..15, LDS tile)
//        B: t=8..12 (bits 14..10, radix-32 pure-register streaming, block-uniform twiddles)
//        C: t=13..22 (bits 9..0): v6 = WAVE-AUTONOMOUS: one wave per 1024-pt chunk,
//           16 complex/lane in registers; stages 13..16 on register bits (scalar twiddles),
//           stages 17..22 on lane bits via shfl_xor; NO barriers until the final
//           dense-store transpose. Kills the per-round vmcnt(0)+s_barrier latency chain.

__global__ __launch_bounds__(256) void fft_pass_a(const float* __restrict__ in,
                                                  const float2* __restrict__ wt,
                                                  uint4* __restrict__ outp)
{
    __shared__ float2 L[4096];   // [g*16 + c], 32 KB
    const int tid = threadIdx.x;
    const int l0  = blockIdx.x << 4;
    const int c   = tid & 15;
    const int qb  = tid >> 4;

    float2 pw1[4], pw2a[4], pw2b[4];
#pragma unroll
    for (int k = 0; k < 4; ++k) { pw1[k] = wt[0]; pw2a[k] = wt[0]; pw2b[k] = wt[1 << 21]; }

    {
        const int c4 = tid & 3, gg = tid >> 2;
#pragma unroll
        for (int k = 0; k < 4; ++k) {
            const int g = gg + (k << 6);
            const f4 v = __builtin_nontemporal_load(
                reinterpret_cast<const f4*>(in + ((size_t)g << 15) + l0 + (c4 << 2)));
            const int base = (g << 4) + (c4 << 2);
            L[base + 0] = make_float2(v[0], 0.f);
            L[base + 1] = make_float2(v[1], 0.f);
            L[base + 2] = make_float2(v[2], 0.f);
            L[base + 3] = make_float2(v[3], 0.f);
        }
    }
    __syncthreads();

#pragma unroll
    for (int rho = 0; rho < 4; ++rho) {
        const int s = rho << 1, H = 128 >> s, Q = H >> 1, lo = 6 - s;
        float2 nw1[4], nw2a[4], nw2b[4];
        if (rho < 3) {
            const int s2 = s + 2, lo2 = 6 - s2;
#pragma unroll
            for (int k = 0; k < 4; ++k) {
                const int qi = (qb << 2) + k;
                const int b  = ((qi >> lo2) << (lo2 + 2)) | (qi & ((1 << lo2) - 1));
                const int jl = (int)(__brev((unsigned)(b >> (8 - s2))) >> (32 - s2));
                const int e  = jl << (21 - s2);
                nw1[k] = wt[e << 1]; nw2a[k] = wt[e]; nw2b[k] = wt[e + (1 << 21)];
            }
        }
#pragma unroll
        for (int k = 0; k < 4; ++k) {
            const int qi = (qb << 2) + k;
            const int b  = ((qi >> lo) << (lo + 2)) | (qi & ((1 << lo) - 1));
            const int iA = (b << 4) + c;
            const float2 A  = L[iA];
            const float2 Bv = L[iA + (Q << 4)];
            const float2 Cv = L[iA + (H << 4)];
            const float2 Dv = L[iA + ((H + Q) << 4)];
            const float2 pC = cmul(pw1[k], Cv), pD = cmul(pw1[k], Dv);
            const float2 tA = cadd(A, pC),  tC = csub(A, pC);
            const float2 tB = cadd(Bv, pD), tD = csub(Bv, pD);
            const float2 p2 = cmul(pw2a[k], tB);
            const float2 p3 = cmul(pw2b[k], tD);
            L[iA]                  = cadd(tA, p2);
            L[iA + (Q << 4)]       = csub(tA, p2);
            L[iA + (H << 4)]       = cadd(tC, p3);
            L[iA + ((H + Q) << 4)] = csub(tC, p3);
        }
        __syncthreads();
        if (rho < 3) {
#pragma unroll
            for (int k = 0; k < 4; ++k) { pw1[k] = nw1[k]; pw2a[k] = nw2a[k]; pw2b[k] = nw2b[k]; }
        }
    }

    {
        const int c4 = tid & 3, gg = tid >> 2;
#pragma unroll
        for (int k = 0; k < 4; ++k) {
            const int g  = gg + (k << 6);
            const int li = (g << 4) + (c4 << 2);
            u4 v;
            v[0] = pk(L[li]); v[1] = pk(L[li + 1]); v[2] = pk(L[li + 2]); v[3] = pk(L[li + 3]);
            __builtin_nontemporal_store(v,
                reinterpret_cast<u4*>(&outp[((size_t)g << 13) + (l0 >> 2) + c4]));
        }
    }
}

// ---- pass B: stages 8..12, radix-32 in registers, no LDS ----
__global__ __launch_bounds__(256) void fft_pass_b(const unsigned* __restrict__ in,
                                                  const float2* __restrict__ wt,
                                                  unsigned* __restrict__ out)
{
    const int tid = threadIdx.x;
    const int h   = blockIdx.x >> 2;
    const int low = ((blockIdx.x & 3) << 8) | tid;
    const unsigned hrev = __brev((unsigned)h) >> 24;
    const unsigned base = ((unsigned)h << 15) | (unsigned)low;

    float2 X[32];
#pragma unroll
    for (int m = 0; m < 32; ++m)
        X[m] = upk(__builtin_nontemporal_load(&in[base + ((unsigned)m << 10)]));

#pragma unroll
    for (int s = 0; s < 5; ++s) {
        const int half = 1 << (4 - s);
#pragma unroll
        for (int j = 0; j < 16; ++j) {
            const int mh = j >> (4 - s);
            const int lo = (mh << (5 - s)) | (j & (half - 1));
            const int hi = lo | half;
            const unsigned cr = crev((unsigned)mh, s);
            const float2 w = wt[(((cr << 8) | hrev) << (14 - s))];
            const float2 p = cmul(w, X[hi]);
            X[hi] = csub(X[lo], p);
            X[lo] = cadd(X[lo], p);
        }
    }
#pragma unroll
    for (int m = 0; m < 32; ++m)
        __builtin_nontemporal_store(pk(X[m]), &out[base + ((unsigned)m << 10)]);
}

// ---- pass C v6: stages 13..22, one WAVE per 1024-pt chunk; barrier-free FFT ----
// x = (j:4 | lane:6); chunk R = (h0<<3)|wave, H = rev13(R).
// stages 13..16: register bits (j), scalar twiddles.
// stages 17..22: lane bits via shfl_xor; twiddles scalar for 17, scalar+select 18/19,
//                per-lane gather 20..22 (8/16/32 lines per wave-instr, block-shared).
// one __syncthreads, then dense 64B-line store via LDS (chunk-major, pitch 1026).
__global__ __launch_bounds__(512, 4) void fft_pass_c(const unsigned* __restrict__ inp,
                                                     const float2* __restrict__ wt,
                                                     float2* __restrict__ out)
{
    extern __shared__ float2 L[];            // 8 * 1026 * 8 B = 65,664 B
    const int tid  = threadIdx.x;
    const int bid  = blockIdx.x;
    const int h0   = ((bid & 7) << 7) | (bid >> 3);   // chunked XCD swizzle
    const int lane = tid & 63;
    const int wv_id = tid >> 6;              // wave id = chunk id within block (0..7)
    const int R    = __builtin_amdgcn_readfirstlane((h0 << 3) | wv_id);  // rev13(H), wave-uniform
    const unsigned H = __brev((unsigned)R) >> 19;

    // ---- load: X[j] = chunk[(j<<6) + lane]  (16 coalesced nontemporal dwords) ----
    float2 X[16];
    {
        const unsigned gb = (H << 10) + (unsigned)lane;
#pragma unroll
        for (int j = 0; j < 16; ++j)
            X[j] = upk(__builtin_nontemporal_load(&inp[gb + ((unsigned)j << 6)]));
    }

    // ---- stages 13..16 on j bits (scalar twiddles) ----
    {   // stage 13: j-bit 3
        const float2 w13 = wt[(unsigned)R << 9];
#pragma unroll
        for (int j = 0; j < 8; ++j) {
            const float2 p = cmul(w13, X[j + 8]);
            X[j + 8] = csub(X[j], p);
            X[j]     = cadd(X[j], p);
        }
    }
#pragma unroll
    for (int jt = 0; jt < 2; ++jt) {         // stage 14: j-bit 2
        const float2 wv = wt[(((unsigned)jt << 13) | (unsigned)R) << 8];
#pragma unroll
        for (int u = 0; u < 4; ++u) {
            const int lo = (jt << 3) + u, hi = lo + 4;
            const float2 p = cmul(wv, X[hi]);
            X[hi] = csub(X[lo], p);
            X[lo] = cadd(X[lo], p);
        }
    }
#pragma unroll
    for (int q = 0; q < 4; ++q) {            // stage 15: j-bit 1
        const float2 wv = wt[((crev((unsigned)q, 2) << 13) | (unsigned)R) << 7];
#pragma unroll
        for (int u = 0; u < 2; ++u) {
            const int lo = (q << 2) + u, hi = lo + 2;
            const float2 p = cmul(wv, X[hi]);
            X[hi] = csub(X[lo], p);
            X[lo] = cadd(X[lo], p);
        }
    }
#pragma unroll
    for (int q = 0; q < 8; ++q) {            // stage 16: j-bit 0
        const float2 wv = wt[((crev((unsigned)q, 3) << 13) | (unsigned)R) << 6];
        const int lo = q << 1, hi = lo + 1;
        const float2 p = cmul(wv, X[hi]);
        X[hi] = csub(X[lo], p);
        X[lo] = cadd(X[lo], p);
    }

    // ---- stages 17..22 on lane bits via shfl_xor ----
    {   // stage 17 (m=32): w depends only on j -> scalar
        const bool hi = (lane & 32) != 0; const float s = hi ? -1.f : 1.f;
#pragma unroll
        for (int j = 0; j < 16; ++j) {
            const float2 wv = wt[((crev((unsigned)j, 4) << 13) | (unsigned)R) << 5];
            X[j] = sbfly(X[j], 32, hi, s, wv);
        }
    }
    {   // stage 18 (m=16): e = base + (lane>>5)<<21 -> 2 scalars + select
        const bool hi = (lane & 16) != 0; const float s = hi ? -1.f : 1.f;
        const int lb5 = lane >> 5;
#pragma unroll
        for (int j = 0; j < 16; ++j) {
            const int base = (int)(((crev((unsigned)j, 4) << 13) | (unsigned)R) << 4);
            const float2 w0 = wt[base], w1 = wt[base + (1 << 21)];
            const float2 wv = lb5 ? w1 : w0;
            X[j] = sbfly(X[j], 16, hi, s, wv);
        }
    }
    {   // stage 19 (m=8): e = base + l4<<21 + l5<<20 -> 4 scalars + 2-level select
        const bool hi = (lane & 8) != 0; const float s = hi ? -1.f : 1.f;
        const int l4 = (lane >> 4) & 1, l5 = lane >> 5;
#pragma unroll
        for (int j = 0; j < 16; ++j) {
            const int base = (int)(((crev((unsigned)j, 4) << 13) | (unsigned)R) << 3);
            const float2 s00 = wt[base],             s01 = wt[base + (1 << 20)];
            const float2 s10 = wt[base + (1 << 21)], s11 = wt[base + (3 << 20)];
            const float2 wa = l5 ? s01 : s00;
            const float2 wb = l5 ? s11 : s10;
            const float2 wv = l4 ? wb : wa;
            X[j] = sbfly(X[j], 8, hi, s, wv);
        }
    }
    {   // stage 20 (m=4): gather, 8 lines/wave-instr
        const bool hi = (lane & 4) != 0; const float s = hi ? -1.f : 1.f;
#pragma unroll
        for (int j = 0; j < 16; ++j) {
            const unsigned xt = ((unsigned)j << 3) | ((unsigned)lane >> 3);   // 7 bits
            const unsigned xr = __brev(xt) >> 25;
            const float2 wv = wt[((xr << 13) | (unsigned)R) << 2];
            X[j] = sbfly(X[j], 4, hi, s, wv);
        }
    }
    {   // stage 21 (m=2): gather, 16 lines/wave-instr
        const bool hi = (lane & 2) != 0; const float s = hi ? -1.f : 1.f;
#pragma unroll
        for (int j = 0; j < 16; ++j) {
            const unsigned xt = ((unsigned)j << 4) | ((unsigned)lane >> 2);   // 8 bits
            const unsigned xr = __brev(xt) >> 24;
            const float2 wv = wt[((xr << 13) | (unsigned)R) << 1];
            X[j] = sbfly(X[j], 2, hi, s, wv);
        }
    }
    {   // stage 22 (m=1): gather, 32 lines/wave-instr (full lines, block-shared)
        const bool hi = (lane & 1) != 0; const float s = hi ? -1.f : 1.f;
#pragma unroll
        for (int j = 0; j < 16; ++j) {
            const unsigned xt = ((unsigned)j << 5) | ((unsigned)lane >> 1);   // 9 bits
            const unsigned xr = __brev(xt) >> 23;
            const float2 wv = wt[(xr << 13) | (unsigned)R];
            X[j] = sbfly(X[j], 1, hi, s, wv);
        }
    }

    // ---- stage results -> LDS (chunk slice, natural order), ONE barrier ----
#pragma unroll
    for (int j = 0; j < 16; ++j)
        L[wv_id * 1026 + (j << 6) + lane] = X[j];
    __syncthreads();

    // ---- dense store: out[rev10(x)<<13 | h0<<3 | c] ; 8 consecutive c = one 64B line ----
    {
        const int l2   = (tid & 3) << 1;     // chunk pair 0,2,4,6
        const int rest = tid >> 2;           // 0..127
#pragma unroll
        for (int k = 0; k < 8; ++k) {
            const int x = (k << 7) | rest;
            const float2 a0 = L[l2 * 1026 + x];
            const float2 a1 = L[(l2 + 1) * 1026 + x];
            const size_t o = ((size_t)(__brev((unsigned)x) >> 22) << 13)
                           | (unsigned)((h0 << 3) | l2);
            f4 sv; sv[0] = a0.x; sv[1] = a0.y; sv[2] = a1.x; sv[3] = a1.y;
            __builtin_nontemporal_store(sv, reinterpret_cast<f4*>(out + o));
        }
    }
}

extern "C" void kernel_launch(void* const* d_in, const int* in_sizes, int n_in,
                              void* d_out, int out_size, void* d_ws, size_t ws_size,
                              hipStream_t stream)
{
    (void)in_sizes; (void)n_in; (void)out_size; (void)ws_size;
    const float*  in = (const float*)d_in[0];
    const float2* wt = (const float2*)d_in[1];
    float2* outc = (float2*)d_out;
    uint4*  buf1 = (uint4*)d_ws;                             // 32 MB packed fp16
    unsigned* buf2 = (unsigned*)((char*)d_ws + (32u << 20)); // 32 MB packed fp16

    static bool attr_done = false;
    if (!attr_done) {
        (void)hipFuncSetAttribute(reinterpret_cast<const void*>(fft_pass_c),
                                  hipFuncAttributeMaxDynamicSharedMemorySize, 8 * 1026 * 8);
        attr_done = true;
    }

    fft_pass_a<<<2048, 256, 0, stream>>>(in, wt, buf1);                            // t=0..7
    fft_pass_b<<<1024, 256, 0, stream>>>((const unsigned*)buf1, wt, buf2);         // t=8..12
    fft_pass_c<<<1024, 512, 8 * 1026 * 8, stream>>>((const unsigned*)buf2, wt, outc); // t=13..22
}

// Round 7
// 203.203 us; speedup vs baseline: 1.2954x; 1.2954x over previous
//
#include <hip/hip_runtime.h>
#include <hip/hip_fp16.h>

__device__ __forceinline__ float2 cadd(float2 a, float2 b) { return make_float2(a.x + b.x, a.y + b.y); }
__device__ __forceinline__ float2 csub(float2 a, float2 b) { return make_float2(a.x - b.x, a.y - b.y); }
__device__ __forceinline__ float2 cmul(float2 w, float2 z) {
    return make_float2(w.x * z.x - w.y * z.y, w.x * z.y + w.y * z.x);
}
__device__ __forceinline__ unsigned pk(float2 z) {
    __half2 h = __floats2half2_rn(z.x, z.y);
    return *reinterpret_cast<unsigned*>(&h);
}
__device__ __forceinline__ float2 upk(unsigned u) {
    __half2 h = *reinterpret_cast<__half2*>(&u);
    return __half22float2(h);
}

__host__ __device__ constexpr unsigned crev(unsigned x, int bits) {
    unsigned r = 0;
    for (int k = 0; k < bits; ++k) r |= ((x >> k) & 1u) << (bits - 1 - k);
    return r;
}

// Butterfly network (DIF):
//   stage t (0..22): pairs (i, i + 2^(22-t)); z'[i] = z[i] + w*z[i+D]; z'[i+D] = z[i] - w*z[i+D]
//   w = weight[ bitrev_t(i >> (23-t)) * 2^(22-t) ];  final: out[rev23(i)] = z[i]
// v7 split (minimize LDS-kernel stages; endpoints byte-identical to the 182µs round-0 config):
//   A : t=0..7   LDS tile kernel (proven)
//   B1: t=8..12  radix-32 in registers, streaming, IN-PLACE on fp16 buffer (proven algebra)
//   B2: t=13..15 radix-8 in registers, streaming, IN-PLACE (new, scalar twiddles)
//   C : t=16..22 16x128-pt LDS kernel with dense bitrev stores (proven, 48µs)

__global__ __launch_bounds__(256) void fft_pass_a(const float* __restrict__ in,
                                                  const float2* __restrict__ wt,
                                                  uint4* __restrict__ outp)
{
    __shared__ float2 L[4096];   // [g*16 + c], 32 KB
    const int tid = threadIdx.x;
    const int l0  = blockIdx.x << 4;
    const int c   = tid & 15;
    const int qb  = tid >> 4;

    float2 pw1[4], pw2a[4], pw2b[4];
#pragma unroll
    for (int k = 0; k < 4; ++k) { pw1[k] = wt[0]; pw2a[k] = wt[0]; pw2b[k] = wt[1 << 21]; }

    {
        const int c4 = tid & 3, gg = tid >> 2;
#pragma unroll
        for (int k = 0; k < 4; ++k) {
            const int g = gg + (k << 6);
            const float4 v = *reinterpret_cast<const float4*>(in + ((size_t)g << 15) + l0 + (c4 << 2));
            const int base = (g << 4) + (c4 << 2);
            L[base + 0] = make_float2(v.x, 0.f);
            L[base + 1] = make_float2(v.y, 0.f);
            L[base + 2] = make_float2(v.z, 0.f);
            L[base + 3] = make_float2(v.w, 0.f);
        }
    }
    __syncthreads();

#pragma unroll
    for (int rho = 0; rho < 4; ++rho) {
        const int s = rho << 1, H = 128 >> s, Q = H >> 1, lo = 6 - s;
        float2 nw1[4], nw2a[4], nw2b[4];
        if (rho < 3) {
            const int s2 = s + 2, lo2 = 6 - s2;
#pragma unroll
            for (int k = 0; k < 4; ++k) {
                const int qi = (qb << 2) + k;
                const int b  = ((qi >> lo2) << (lo2 + 2)) | (qi & ((1 << lo2) - 1));
                const int jl = (int)(__brev((unsigned)(b >> (8 - s2))) >> (32 - s2));
                const int e  = jl << (21 - s2);
                nw1[k] = wt[e << 1]; nw2a[k] = wt[e]; nw2b[k] = wt[e + (1 << 21)];
            }
        }
#pragma unroll
        for (int k = 0; k < 4; ++k) {
            const int qi = (qb << 2) + k;
            const int b  = ((qi >> lo) << (lo + 2)) | (qi & ((1 << lo) - 1));
            const int iA = (b << 4) + c;
            const float2 A  = L[iA];
            const float2 Bv = L[iA + (Q << 4)];
            const float2 Cv = L[iA + (H << 4)];
            const float2 Dv = L[iA + ((H + Q) << 4)];
            const float2 pC = cmul(pw1[k], Cv), pD = cmul(pw1[k], Dv);
            const float2 tA = cadd(A, pC),  tC = csub(A, pC);
            const float2 tB = cadd(Bv, pD), tD = csub(Bv, pD);
            const float2 p2 = cmul(pw2a[k], tB);
            const float2 p3 = cmul(pw2b[k], tD);
            L[iA]                  = cadd(tA, p2);
            L[iA + (Q << 4)]       = csub(tA, p2);
            L[iA + (H << 4)]       = cadd(tC, p3);
            L[iA + ((H + Q) << 4)] = csub(tC, p3);
        }
        __syncthreads();
        if (rho < 3) {
#pragma unroll
            for (int k = 0; k < 4; ++k) { pw1[k] = nw1[k]; pw2a[k] = nw2a[k]; pw2b[k] = nw2b[k]; }
        }
    }

    {
        const int c4 = tid & 3, gg = tid >> 2;
#pragma unroll
        for (int k = 0; k < 4; ++k) {
            const int g  = gg + (k << 6);
            const int li = (g << 4) + (c4 << 2);
            uint4 v;
            v.x = pk(L[li]); v.y = pk(L[li + 1]); v.z = pk(L[li + 2]); v.w = pk(L[li + 3]);
            outp[((size_t)g << 13) + (l0 >> 2) + c4] = v;
        }
    }
}

// ---- B1: stages 8..12, radix-32 in registers, in-place ----
// i = (h:8 | m:5 | low:10). Block: h = blk>>2 (uniform), low = (blk&3)<<8 | tid.
__global__ __launch_bounds__(256) void fft_pass_b1(unsigned* __restrict__ buf,
                                                   const float2* __restrict__ wt)
{
    const int tid = threadIdx.x;
    const int h   = blockIdx.x >> 2;
    const int low = ((blockIdx.x & 3) << 8) | tid;
    const unsigned hrev = __brev((unsigned)h) >> 24;
    const unsigned base = ((unsigned)h << 15) | (unsigned)low;

    float2 X[32];
#pragma unroll
    for (int m = 0; m < 32; ++m) X[m] = upk(buf[base + ((unsigned)m << 10)]);

#pragma unroll
    for (int s = 0; s < 5; ++s) {
        const int half = 1 << (4 - s);
#pragma unroll
        for (int j = 0; j < 16; ++j) {
            const int mh = j >> (4 - s);
            const int lo = (mh << (5 - s)) | (j & (half - 1));
            const int hi = lo | half;
            const unsigned cr = crev((unsigned)mh, s);
            const float2 w = wt[(((cr << 8) | hrev) << (14 - s))];
            const float2 p = cmul(w, X[hi]);
            X[hi] = csub(X[lo], p);
            X[lo] = cadd(X[lo], p);
        }
    }
#pragma unroll
    for (int m = 0; m < 32; ++m) buf[base + ((unsigned)m << 10)] = pk(X[m]);
}

// ---- B2: stages 13..15, radix-8 in registers, in-place ----
// i = (P:13 | n:3 | r:7). Thread: fixed (P, r); registers over n. R = rev13(P) wave-uniform.
__global__ __launch_bounds__(256) void fft_pass_b2(unsigned* __restrict__ buf,
                                                   const float2* __restrict__ wt)
{
    const int tid = threadIdx.x;
    const int P   = __builtin_amdgcn_readfirstlane((blockIdx.x << 1) | (tid >> 7));
    const int r   = tid & 127;
    const unsigned R = __brev((unsigned)P) >> 19;
    const unsigned base = ((unsigned)P << 10) | (unsigned)r;

    float2 X[8];
#pragma unroll
    for (int n = 0; n < 8; ++n) X[n] = upk(buf[base + ((unsigned)n << 7)]);

    {   // stage 13: flips n-bit2; w = wt[rev13(P) << 9] (uniform)
        const float2 w = wt[R << 9];
#pragma unroll
        for (int n = 0; n < 4; ++n) {
            const float2 p = cmul(w, X[n + 4]);
            X[n + 4] = csub(X[n], p);
            X[n]     = cadd(X[n], p);
        }
    }
#pragma unroll
    for (int n2 = 0; n2 < 2; ++n2) {   // stage 14: flips n-bit1; w = wt[((n2<<13)|R)<<8]
        const float2 w = wt[(((unsigned)n2 << 13) | R) << 8];
#pragma unroll
        for (int u = 0; u < 2; ++u) {
            const int lo = (n2 << 2) + u, hi = lo + 2;
            const float2 p = cmul(w, X[hi]);
            X[hi] = csub(X[lo], p);
            X[lo] = cadd(X[lo], p);
        }
    }
#pragma unroll
    for (int q = 0; q < 4; ++q) {      // stage 15: flips n-bit0; w = wt[((rev2(q)<<13)|R)<<7]
        const float2 w = wt[((crev((unsigned)q, 2) << 13) | R) << 7];
        const int lo = q << 1, hi = lo + 1;
        const float2 p = cmul(w, X[hi]);
        X[hi] = csub(X[lo], p);
        X[lo] = cadd(X[lo], p);
    }

#pragma unroll
    for (int n = 0; n < 8; ++n) buf[base + ((unsigned)n << 7)] = pk(X[n]);
}

// ---- C: stages 16..22 (byte-identical to the proven 48µs round-0 pass_c) ----
__global__ __launch_bounds__(256, 8) void fft_pass_c(const uint4* __restrict__ inp,
                                                     const float2* __restrict__ wt,
                                                     float2* __restrict__ out)
{
    __shared__ float2 L[16 * 129];    // 16 chunks, pitch 129 -> ~16.1 KB, 8 blocks/CU
    const int tid = threadIdx.x;
    const int h0  = blockIdx.x;       // 0..4095

    const int lam = tid & 15;
    const int bq  = tid >> 4;         // 0..15
    const int rH  = (h0 << 4) + lam;  // rev16(H) for this lane's chunk

    float2 pw1[2], pw2a[2], pw2b[2];
#pragma unroll
    for (int k = 0; k < 2; ++k) {
        pw1[k]  = wt[rH << 6];
        pw2a[k] = wt[rH << 5];
        pw2b[k] = wt[(rH << 5) + (1 << 21)];
    }

    // ---- load packed fp16: 16 chunks of 128 complex (512 B granules) ----
    {
        const int f  = tid & 31;      // uint4 slot within chunk
        const int ll = tid >> 5;      // 0..7
#pragma unroll
        for (int k = 0; k < 2; ++k) {
            const int lm = ll + (k << 3);
            const int H  = (int)(__brev((unsigned)((h0 << 4) + lm)) >> 16);
            const uint4 v = inp[((size_t)H << 5) + f];
            const int li = lm * 129 + (f << 2);
            L[li]     = upk(v.x);
            L[li + 1] = upk(v.y);
            L[li + 2] = upk(v.z);
            L[li + 3] = upk(v.w);
        }
    }
    __syncthreads();

    // ---- stages 16..21 as 3 radix-4 rounds ----
    float2 pr2[4];
#pragma unroll
    for (int rho = 0; rho < 3; ++rho) {
        const int s = rho << 1, H = 64 >> s, Q = H >> 1, lo = 5 - s;
        float2 nw1[2], nw2a[2], nw2b[2];
        if (rho < 2) {
            const int s2 = s + 2, lo2 = 5 - s2;
#pragma unroll
            for (int k = 0; k < 2; ++k) {
                const int qi = (bq << 1) + k;
                const int b  = ((qi >> lo2) << (lo2 + 2)) | (qi & ((1 << lo2) - 1));
                const int jl = (int)(__brev((unsigned)(b >> (7 - s2))) >> (32 - s2));
                const int e  = (rH << (5 - s2)) + (jl << (21 - s2));
                nw1[k] = wt[e << 1]; nw2a[k] = wt[e]; nw2b[k] = wt[e + (1 << 21)];
            }
        } else {
#pragma unroll
            for (int k = 0; k < 4; ++k) {
                const int pb = (bq << 2) + k;
                const int jl = (int)(__brev((unsigned)pb) >> 26);
                pr2[k] = wt[rH + (jl << 16)];
            }
        }
#pragma unroll
        for (int k = 0; k < 2; ++k) {
            const int qi = (bq << 1) + k;     // 0..31
            const int b  = ((qi >> lo) << (lo + 2)) | (qi & ((1 << lo) - 1));
            const int iA = lam * 129 + b;
            const float2 A  = L[iA];
            const float2 Bv = L[iA + Q];
            const float2 Cv = L[iA + H];
            const float2 Dv = L[iA + H + Q];
            const float2 pC = cmul(pw1[k], Cv), pD = cmul(pw1[k], Dv);
            const float2 tA = cadd(A, pC),  tC = csub(A, pC);
            const float2 tB = cadd(Bv, pD), tD = csub(Bv, pD);
            const float2 p2 = cmul(pw2a[k], tB);
            const float2 p3 = cmul(pw2b[k], tD);
            L[iA]         = cadd(tA, p2);
            L[iA + Q]     = csub(tA, p2);
            L[iA + H]     = cadd(tC, p3);
            L[iA + H + Q] = csub(tC, p3);
        }
        __syncthreads();
        if (rho < 2) {
#pragma unroll
            for (int k = 0; k < 2; ++k) { pw1[k] = nw1[k]; pw2a[k] = nw2a[k]; pw2b[k] = nw2b[k]; }
        }
    }

    // ---- final radix-2 stage (t=22, stride 1) ----
    {
#pragma unroll
        for (int k = 0; k < 4; ++k) {
            const int pb = (bq << 2) + k;     // 0..63
            const int b  = pb << 1;
            const int iA = lam * 129 + b;
            const float2 A  = L[iA];
            const float2 Bv = L[iA + 1];
            const float2 p  = cmul(pr2[k], Bv);
            L[iA]     = cadd(A, p);
            L[iA + 1] = csub(A, p);
        }
    }
    __syncthreads();

    // ---- store fp32 with bit-reversal: out[rev7(g)*2^16 + h0*16 + lam] = L[lam][g] ----
    {
        const int l2 = (tid & 7) << 1;        // even lam (0..14)
        const int gb = tid >> 3;              // 0..31
#pragma unroll
        for (int k = 0; k < 4; ++k) {
            const int g    = gb + (k << 5);   // 0..127
            const int grev = (int)(__brev((unsigned)g) >> 25);   // rev7(g)
            const float2 a0 = L[l2 * 129 + g];
            const float2 a1 = L[(l2 + 1) * 129 + g];
            const size_t o = ((size_t)grev << 16) + (h0 << 4) + l2;
            *reinterpret_cast<float4*>(out + o) = make_float4(a0.x, a0.y, a1.x, a1.y);
        }
    }
}

extern "C" void kernel_launch(void* const* d_in, const int* in_sizes, int n_in,
                              void* d_out, int out_size, void* d_ws, size_t ws_size,
                              hipStream_t stream)
{
    (void)in_sizes; (void)n_in; (void)out_size; (void)ws_size;
    const float*  in = (const float*)d_in[0];
    const float2* wt = (const float2*)d_in[1];
    float2* outc = (float2*)d_out;
    uint4*  buf1 = (uint4*)d_ws;                  // 32 MB packed fp16 (in-place for B1/B2)
    unsigned* buf1w = (unsigned*)d_ws;

    fft_pass_a <<<2048, 256, 0, stream>>>(in, wt, buf1);      // t=0..7   : in  -> buf1
    fft_pass_b1<<<1024, 256, 0, stream>>>(buf1w, wt);          // t=8..12  : buf1 in-place
    fft_pass_b2<<<4096, 256, 0, stream>>>(buf1w, wt);          // t=13..15 : buf1 in-place
    fft_pass_c <<<4096, 256, 0, stream>>>(buf1, wt, outc);     // t=16..22 : buf1 -> out
}